// Round 10
// baseline (273.098 us; speedup 1.0000x reference)
//
#include <hip/hip_runtime.h>

// B=2, F=T=2048, HIDDEN=1024 (16 heads x 64)
// Round 16 = round-15 with the LDS unit bug fixed: Ks per-buffer stride is
// 8192 u16 (16 KB), not 16384 (that was bytes; +16384 u16 landed in Ps and
// corrupted P staging on odd iterations -> the 4.6e-2 absmax).
// attn: V LDS staging dropped (Vt[head][h][t] is PV-A-fragment-native, L2-hot);
// K double-buffered in freed LDS -> ONE barrier/iter; K keeps T14 reg-prefetch.
// prep/gemm = round-8 verbatim.
// Banned by measurement: setprio in MFMA bodies (r12 spills), VALU l-sum (r9),
// transposed mask words (r10 XCD ping-pong), mask-pack-in-gemm z-slices (r11).

typedef short v8s __attribute__((ext_vector_type(8)));
typedef float v4f __attribute__((ext_vector_type(4)));
typedef unsigned short u16;
typedef unsigned int   u32;
typedef unsigned long long u64;

constexpr float QSCALE = 0.18033688011112042f;  // 0.125 * log2(e)

__device__ __forceinline__ u16 f2bf(float f) {
    u32 u = __builtin_bit_cast(u32, f);
    u += 0x7fffu + ((u >> 16) & 1u);
    return (u16)(u >> 16);
}

// truncating bf16 pair pack: {b[31:16], a[31:16]} in ONE v_perm_b32
__device__ __forceinline__ u32 pack_trunc(float a, float b) {
    return __builtin_amdgcn_perm(__builtin_bit_cast(u32, b),
                                 __builtin_bit_cast(u32, a), 0x07060302u);
}

// ROUNDING bf16 pair pack (same rounding as f2bf)
__device__ __forceinline__ u32 pack_rnd(u32 ua, u32 ub) {
    ua += 0x7fffu + ((ua >> 16) & 1u);
    ub += 0x7fffu + ((ub >> 16) & 1u);
    return __builtin_amdgcn_perm(ub, ua, 0x07060302u);
}

// 8 fp32 (2 uint4) -> 8 bf16 (1 uint4), element order preserved
__device__ __forceinline__ uint4 cvt8(uint4 lo, uint4 hi) {
    uint4 r;
    r.x = pack_rnd(lo.x, lo.y);
    r.y = pack_rnd(lo.z, lo.w);
    r.z = pack_rnd(hi.x, hi.y);
    r.w = pack_rnd(hi.z, hi.w);
    return r;
}

__device__ __forceinline__ v8s ld8(const u16* p) {
    return *reinterpret_cast<const v8s*>(p);
}

// ---------------- prep: W transpose+cvt | mask pack (batched) ----------------
__global__ __launch_bounds__(256) void prep(
    const float* __restrict__ Wq, const float* __restrict__ Wk, const float* __restrict__ Wv,
    u16* __restrict__ Wqt, u16* __restrict__ Wkt, u16* __restrict__ Wvt,
    const int* __restrict__ mask, u64* __restrict__ words) {
    __shared__ float tile[32][33];
    const int bid = blockIdx.x, tid = threadIdx.x;
    if (bid < 3072) {
        const int zz = bid >> 10, rem = bid & 1023;
        const float* W = zz == 0 ? Wq : (zz == 1 ? Wk : Wv);
        u16* Wt = zz == 0 ? Wqt : (zz == 1 ? Wkt : Wvt);
        const int tx = tid & 31, ty = tid >> 5;
        const int n0 = (rem & 31) * 32, k0 = (rem >> 5) * 32;
        for (int i = 0; i < 4; i++)
            tile[ty + i * 8][tx] = W[(size_t)(k0 + ty + i * 8) * 1024 + n0 + tx];
        __syncthreads();
        for (int i = 0; i < 4; i++)
            Wt[(size_t)(n0 + ty + i * 8) * 1024 + k0 + tx] = f2bf(tile[tx][ty + i * 8]);
    } else {
        // mask pack: 4096 blocks x 4 waves x 8 words (64 ints each), ILP 8
        const int lane = tid & 63;
        const int g0 = (bid - 3072) * 32 + (tid >> 6) * 8;
        const int* mp = mask + (size_t)g0 * 64 + lane;
        u64* wp = words + g0;
        #pragma unroll
        for (int i = 0; i < 8; i++) {
            const u64 bits = __ballot(mp[(size_t)i * 64] != 0);
            if (lane == 0) wp[i] = bits;
        }
    }
}

// ---------------- z-fused bf16 GEMM, BK=64: C[4096][1024] = A @ W^T + bias ----
__global__ __launch_bounds__(256, 3) void gemm_qkv(
    const float* __restrict__ Xf32, const float* __restrict__ Xt32,
    const u16* __restrict__ Wqt, const u16* __restrict__ Wkt, const u16* __restrict__ Wvt,
    const float* __restrict__ bq, const float* __restrict__ bk, const float* __restrict__ bv,
    u16* __restrict__ Qb, u16* __restrict__ Kb, u16* __restrict__ Vtb) {
    const int z = blockIdx.z;
    const float* A    = z == 0 ? Xf32 : Xt32;
    const u16* Bt     = z == 0 ? Wqt : (z == 1 ? Wkt : Wvt);
    const float* bias = z == 0 ? bq : (z == 1 ? bk : bv);
    u16* C            = z == 0 ? Qb : (z == 1 ? Kb : Vtb);
    const int mode    = (z == 2);
    const float sc    = (z == 0) ? QSCALE : 1.0f;

    __shared__ u16 As[2][128][32];   // [khalf][row][32] 16 KB
    __shared__ u16 Bs[2][128][32];
    const uint4* Ag = reinterpret_cast<const uint4*>(A);   // fp32: 256 uint4/row
    const uint4* Bg = reinterpret_cast<const uint4*>(Bt);  // bf16: 128 uint4/row

    const int tid = threadIdx.x;
    const int lane = tid & 63, wave = tid >> 6;
    const int quad = lane >> 4, l16 = lane & 15;
    const int wm = wave >> 1, wn = wave & 1;
    const int m0 = blockIdx.x * 128, n0 = blockIdx.y * 128;

    const int cg  = (lane & 3) ^ ((lane >> 3) & 3);
    const int sw8 = (quad ^ ((l16 >> 1) & 3)) * 8;

    const int gi0 = wave * 4;
    const uint4 *ap0, *ap1, *ap2, *ap3, *bp0, *bp1, *bp2, *bp3;
    {
        const int rl = lane >> 2;
        const int rb0 = ((gi0 + 0) & 7) * 16 + rl, kh0 = (gi0 + 0) >> 3;
        const int rb1 = ((gi0 + 1) & 7) * 16 + rl, kh1 = (gi0 + 1) >> 3;
        const int rb2 = ((gi0 + 2) & 7) * 16 + rl, kh2 = (gi0 + 2) >> 3;
        const int rb3 = ((gi0 + 3) & 7) * 16 + rl, kh3 = (gi0 + 3) >> 3;
        // fp32 A: lane covers 8 floats = 2 consecutive uint4 at (kh*4+cg)*2
        ap0 = Ag + (size_t)(m0 + rb0) * 256 + (kh0 * 4 + cg) * 2;
        ap1 = Ag + (size_t)(m0 + rb1) * 256 + (kh1 * 4 + cg) * 2;
        ap2 = Ag + (size_t)(m0 + rb2) * 256 + (kh2 * 4 + cg) * 2;
        ap3 = Ag + (size_t)(m0 + rb3) * 256 + (kh3 * 4 + cg) * 2;
        bp0 = Bg + (size_t)(n0 + rb0) * 128 + kh0 * 4 + cg;
        bp1 = Bg + (size_t)(n0 + rb1) * 128 + kh1 * 4 + cg;
        bp2 = Bg + (size_t)(n0 + rb2) * 128 + kh2 * 4 + cg;
        bp3 = Bg + (size_t)(n0 + rb3) * 128 + kh3 * 4 + cg;
    }
    uint4* da = reinterpret_cast<uint4*>((u16*)As + gi0 * 512) + lane;
    uint4* db = reinterpret_cast<uint4*>((u16*)Bs + gi0 * 512) + lane;

    v4f acc[4][4];
    for (int i = 0; i < 4; i++)
        for (int j = 0; j < 4; j++) acc[i][j] = (v4f)0.0f;

    // prologue: load K-slice 0 (A fp32 raw + B bf16), convert A
    uint4 a0l = ap0[0], a0h = ap0[1]; ap0 += 16;
    uint4 a1l = ap1[0], a1h = ap1[1]; ap1 += 16;
    uint4 a2l = ap2[0], a2h = ap2[1]; ap2 += 16;
    uint4 a3l = ap3[0], a3h = ap3[1]; ap3 += 16;
    uint4 sb0 = *bp0; bp0 += 8;
    uint4 sb1 = *bp1; bp1 += 8;
    uint4 sb2 = *bp2; bp2 += 8;
    uint4 sb3 = *bp3; bp3 += 8;
    uint4 ca0 = cvt8(a0l, a0h);
    uint4 ca1 = cvt8(a1l, a1h);
    uint4 ca2 = cvt8(a2l, a2h);
    uint4 ca3 = cvt8(a3l, a3h);

    for (int k0 = 0; k0 < 16; k0++) {
        __syncthreads();
        da[0]   = ca0;  da[64]  = ca1;  da[128] = ca2;  da[192] = ca3;
        db[0]   = sb0;  db[64]  = sb1;  db[128] = sb2;  db[192] = sb3;
        __syncthreads();

        if (k0 < 15) {
            a0l = ap0[0]; a0h = ap0[1]; ap0 += 16;
            a1l = ap1[0]; a1h = ap1[1]; ap1 += 16;
            a2l = ap2[0]; a2h = ap2[1]; ap2 += 16;
            a3l = ap3[0]; a3h = ap3[1]; ap3 += 16;
            sb0 = *bp0; bp0 += 8;
            sb1 = *bp1; bp1 += 8;
            sb2 = *bp2; bp2 += 8;
            sb3 = *bp3; bp3 += 8;
        }

        #pragma unroll
        for (int kk = 0; kk < 2; kk++) {
            v8s af[4], bf[4];
            #pragma unroll
            for (int mt = 0; mt < 4; mt++) af[mt] = ld8(&As[kk][wm * 64 + mt * 16 + l16][sw8]);
            #pragma unroll
            for (int nt = 0; nt < 4; nt++) bf[nt] = ld8(&Bs[kk][wn * 64 + nt * 16 + l16][sw8]);
            #pragma unroll
            for (int mt = 0; mt < 4; mt++)
                #pragma unroll
                for (int nt = 0; nt < 4; nt++)
                    acc[mt][nt] = __builtin_amdgcn_mfma_f32_16x16x32_bf16(af[mt], bf[nt], acc[mt][nt], 0, 0, 0);
        }

        if (k0 < 15) {               // convert AFTER compute: loads have arrived
            ca0 = cvt8(a0l, a0h);
            ca1 = cvt8(a1l, a1h);
            ca2 = cvt8(a2l, a2h);
            ca3 = cvt8(a3l, a3h);
        }
    }

    #pragma unroll
    for (int nt = 0; nt < 4; nt++) {
        const int col = n0 + wn * 64 + nt * 16 + l16;
        const float bvv = bias[col];
        #pragma unroll
        for (int mt = 0; mt < 4; mt++) {
            const int mbase = m0 + wm * 64 + mt * 16 + quad * 4;
            if (mode == 0) {
                for (int r = 0; r < 4; r++)
                    C[(size_t)(mbase + r) * 1024 + col] = f2bf((acc[mt][nt][r] + bvv) * sc);
            } else {
                const int b = mbase >> 11, t = mbase & 2047;
                const int head = col >> 6, h = col & 63;
                ushort4 pk;
                pk.x = f2bf(acc[mt][nt][0] + bvv);
                pk.y = f2bf(acc[mt][nt][1] + bvv);
                pk.z = f2bf(acc[mt][nt][2] + bvv);
                pk.w = f2bf(acc[mt][nt][3] + bvv);
                *reinterpret_cast<ushort4*>(&C[(size_t)((b * 16 + head) * 64 + h) * 2048 + t]) = pk;
            }
        }
    }
}

// ---------------- fused flash attention: V L2-direct, K double-buffered ----
// Q,K: bf16 [B][F/T][16][64] (Q pre-scaled); Vt: bf16 [B][16][64][2048]
// grid (32 bh, 16 f); block 512 = 8 waves. Wave w: q-rows (w&3)*32.., t-half w>>2.
// Per iter: ONE barrier. K(it+1) regs->ds_write into buf^1 (T14, 2 instr/wave);
// V fragments read straight from global (L2-hot, layout-native, no transpose);
// QK^T from Ks[buf]; softmax in-reg; P via per-wave LDS; PV with accL MFMA l-sum.
// Per-buffer stride = 8192 u16 (16 KB) -- r15's 16384 was the bug.
__global__ __launch_bounds__(512, 4) void attn_fused(
    const u16* __restrict__ Qb, const u16* __restrict__ Kb,
    const u16* __restrict__ Vtb, const u64* __restrict__ mw,
    float* __restrict__ out) {
    __shared__ u16 Ks[2][2][2][64][32];  // [buf][thalf][khalf][t][32]  32 KB
    __shared__ u32 Ps[8 * 1152];         // per-wave P; epilogue buffer (36 KB)

    const int tid = threadIdx.x;
    const int lane = tid & 63, wave = tid >> 6;
    const int quad = lane >> 4, l16 = lane & 15;
    const int fwave = wave & 3, tw = wave >> 2;
    const int b = blockIdx.x >> 4, head = blockIdx.x & 15;
    const int f0 = blockIdx.y * 128;

    const uint4* Kg = reinterpret_cast<const uint4*>(Kb);
    const size_t vb16 = (size_t)(b * 16 + head) * 131072;   // u16 units

    const int cg  = (lane & 3) ^ ((lane >> 3) & 3);
    const int sw8 = (quad ^ ((l16 >> 1) & 3)) * 8;

    // Q-fragments in registers for the whole kernel (B-operand layout)
    v8s qf[2][2];
    #pragma unroll
    for (int kk = 0; kk < 2; kk++)
        #pragma unroll
        for (int qh = 0; qh < 2; qh++)
            qf[kk][qh] = ld8(Qb + ((size_t)(b * 2048 + f0 + fwave * 32 + qh * 16 + l16) * 16 + head) * 64
                                + kk * 32 + quad * 8);

    // ones A-fragment for the l-sum MFMA (bf16 1.0 = 0x3F80)
    v8s ones;
    #pragma unroll
    for (int i = 0; i < 8; i++) ones[i] = (short)0x3F80;

    // K staging: 16 instrs/iter over 8 waves = 2 per wave (T14 reg-prefetch).
    // Instr g covers 1 KB at (u16*)Ks + buf*8192 + g*512, lane slot lane*16 B.
    const uint4 *sp0, *sp1;
    {
        const int rl = lane >> 2;
        const int g0 = wave * 2;
        #define KPTR(g) (Kg + ((size_t)(b * 2048 + ((g) >> 3) * 1024 + ((g) & 3) * 16 + rl) * 16 + head) * 8 \
                            + (((g) >> 2) & 1) * 4 + cg)
        sp0 = KPTR(g0); sp1 = KPTR(g0 + 1);
        #undef KPTR
    }
    uint4* sd4a = reinterpret_cast<uint4*>((u16*)Ks + wave * 1024) + lane;          // buf0
    uint4* sd4b = reinterpret_cast<uint4*>((u16*)Ks + 8192 + wave * 1024) + lane;   // buf1

    v4f accO[2][4], accL[2];
    #pragma unroll
    for (int qh = 0; qh < 2; qh++) {
        accL[qh] = (v4f)0.0f;
        for (int ht = 0; ht < 4; ht++) accO[qh][ht] = (v4f)0.0f;
    }

    u32* myPs = Ps + wave * 1152;
    const u64* mrow = mw + (size_t)(b * 2048 + f0 + fwave * 32 + l16) * 32 + tw * 16;

    // prologue: K(0) -> regs -> buf0; K(1) -> regs; barrier
    uint4 k0a = *sp0; sp0 += 8192;
    uint4 k0b = *sp1; sp1 += 8192;
    sd4a[0]  = k0a;
    sd4a[64] = k0b;
    k0a = *sp0; sp0 += 8192;
    k0b = *sp1; sp1 += 8192;
    __syncthreads();

    for (int it = 0; it < 16; it++) {
        // stage K(it+1) into the write-buf; issue K(it+2) loads
        if (it < 15) {
            uint4* wd = (it & 1) ? sd4a : sd4b;
            wd[0]  = k0a;
            wd[64] = k0b;
            if (it < 14) {
                k0a = *sp0; sp0 += 8192;
                k0b = *sp1; sp1 += 8192;
            }
        }

        // V fragments for kk=0 issued EARLY (no barrier dependency; L2-hot);
        // they hide under QK^T + softmax.
        const u16* vpi = Vtb + vb16 + tw * 1024 + it * 64 + quad * 8;
        v8s vf0[4];
        #pragma unroll
        for (int ht = 0; ht < 4; ht++)
            vf0[ht] = ld8(vpi + (size_t)(ht * 16 + l16) * 2048);

        const u16* kb = (const u16*)Ks + (it & 1) * 8192;

        // S^T = K . Q^T : s[qh][mt], t = mt*16 + quad*4 + r, q-row = qh*16 + l16
        v4f s[2][4];
        #pragma unroll
        for (int qh = 0; qh < 2; qh++)
            for (int mt = 0; mt < 4; mt++) s[qh][mt] = (v4f)0.0f;
        #pragma unroll
        for (int kk = 0; kk < 2; kk++) {
            v8s kf[4];
            #pragma unroll
            for (int mt = 0; mt < 4; mt++)
                kf[mt] = ld8(kb + tw * 4096 + kk * 2048 + (mt * 16 + l16) * 32 + sw8);
            #pragma unroll
            for (int qh = 0; qh < 2; qh++)
                #pragma unroll
                for (int mt = 0; mt < 4; mt++)
                    s[qh][mt] = __builtin_amdgcn_mfma_f32_16x16x32_bf16(kf[mt], qf[kk][qh], s[qh][mt], 0, 0, 0);
        }

        // p = mask ? exp2(s) : 0  (no max pass; Q pre-scaled)
        u32 pk[2][8];
        #pragma unroll
        for (int qh = 0; qh < 2; qh++) {
            const u64 w = mrow[qh * 512 + it];
            const u32 lo = (u32)(w >> (quad * 4));
            const u32 hi = (u32)(w >> (quad * 4 + 32));
            #pragma unroll
            for (int mt = 0; mt < 4; mt++) {
                const u32 bits = ((mt & 2) ? hi : lo) >> ((mt & 1) * 16);
                float p[4];
                #pragma unroll
                for (int r = 0; r < 4; r++) {
                    const float e = __builtin_amdgcn_exp2f(s[qh][mt][r]);
                    p[r] = ((bits >> r) & 1u) ? e : 0.0f;
                }
                pk[qh][mt * 2]     = pack_trunc(p[0], p[1]);
                pk[qh][mt * 2 + 1] = pack_trunc(p[2], p[3]);
            }
        }

        // P -> per-wave LDS (wave-private: no barrier)
        #pragma unroll
        for (int qh = 0; qh < 2; qh++) {
            const int row = qh * 16 + l16;
            #pragma unroll
            for (int mt = 0; mt < 4; mt++)
                *reinterpret_cast<uint2*>(&myPs[row * 36 + mt * 8 + quad * 2]) =
                    make_uint2(pk[qh][mt * 2], pk[qh][mt * 2 + 1]);
        }

        // O^T += V . P^T ; l += ones . P^T  (same rounded P as numerator)
        #pragma unroll
        for (int kk = 0; kk < 2; kk++) {
            v8s vf[4];
            #pragma unroll
            for (int ht = 0; ht < 4; ht++)
                vf[ht] = (kk == 0) ? vf0[ht]
                                   : ld8(vpi + (size_t)(ht * 16 + l16) * 2048 + 32);
            #pragma unroll
            for (int qh = 0; qh < 2; qh++) {
                const v8s pf = *reinterpret_cast<const v8s*>(
                    &myPs[(qh * 16 + l16) * 36 + kk * 16 + quad * 4]);
                #pragma unroll
                for (int ht = 0; ht < 4; ht++)
                    accO[qh][ht] = __builtin_amdgcn_mfma_f32_16x16x32_bf16(vf[ht], pf, accO[qh][ht], 0, 0, 0);
                accL[qh] = __builtin_amdgcn_mfma_f32_16x16x32_bf16(ones, pf, accL[qh], 0, 0, 0);
            }
        }

        __syncthreads();             // single barrier: buf swap + Ps reuse safety
    }

    // ---- epilogue: combine the two t-halves in LDS ----
    float* fb = (float*)Ps;               // 9216 floats: 4 regions x 64 lanes x 36
    if (tw == 1) {
        float* wdst = fb + fwave * 2304 + lane * 36;
        #pragma unroll
        for (int qh = 0; qh < 2; qh++)
            #pragma unroll
            for (int ht = 0; ht < 4; ht++)
                *reinterpret_cast<v4f*>(wdst + (qh * 4 + ht) * 4) = accO[qh][ht];
        wdst[32] = accL[0][0];
        wdst[33] = accL[1][0];
    }
    __syncthreads();
    if (tw == 0) {
        const float* rsrc = fb + fwave * 2304 + lane * 36;
        float inv[2];
        #pragma unroll
        for (int qh = 0; qh < 2; qh++)
            inv[qh] = 1.0f / (accL[qh][0] + rsrc[32 + qh]);
        #pragma unroll
        for (int qh = 0; qh < 2; qh++) {
            const size_t ro = (size_t)(b * 2048 + f0 + fwave * 32 + qh * 16 + l16) * 1024 + head * 64;
            #pragma unroll
            for (int ht = 0; ht < 4; ht++) {
                const v4f p = *reinterpret_cast<const v4f*>(rsrc + (qh * 4 + ht) * 4);
                float4 o;
                o.x = (accO[qh][ht][0] + p[0]) * inv[qh];
                o.y = (accO[qh][ht][1] + p[1]) * inv[qh];
                o.z = (accO[qh][ht][2] + p[2]) * inv[qh];
                o.w = (accO[qh][ht][3] + p[3]) * inv[qh];
                *reinterpret_cast<float4*>(&out[ro + ht * 16 + quad * 4]) = o;
            }
        }
    }
}

extern "C" void kernel_launch(void* const* d_in, const int* in_sizes, int n_in,
                              void* d_out, int out_size, void* d_ws, size_t ws_size,
                              hipStream_t stream) {
    const float* from = (const float*)d_in[0];
    const float* to   = (const float*)d_in[1];
    const int*   mask = (const int*)d_in[2];
    const float* Wq = (const float*)d_in[3];
    const float* bq = (const float*)d_in[4];
    const float* Wk = (const float*)d_in[5];
    const float* bk = (const float*)d_in[6];
    const float* Wv = (const float*)d_in[7];
    const float* bv = (const float*)d_in[8];
    float* out = (float*)d_out;

    u16* Wqt = (u16*)d_ws;            // 1024x1024 bf16 each
    u16* Wkt = Wqt + 1048576;
    u16* Wvt = Wkt + 1048576;
    u16* Qb  = Wvt + 1048576;         // 4096x1024
    u16* Kb  = Qb  + 4194304;
    u16* Vtb = Kb  + 4194304;         // [2][16][64][2048]
    u64* mwords = (u64*)(Vtb + 4194304);  // 2*2048*32 words, row-major [row][tword]

    prep<<<7168, 256, 0, stream>>>(Wq, Wk, Wv, Wqt, Wkt, Wvt, mask, mwords);

    gemm_qkv<<<dim3(32, 8, 3), 256, 0, stream>>>(from, to, Wqt, Wkt, Wvt, bq, bk, bv,
                                                 Qb, Kb, Vtb);

    attn_fused<<<dim3(32, 16), 512, 0, stream>>>(Qb, Kb, Vtb, mwords, out);
}

// Round 11
// 253.641 us; speedup vs baseline: 1.0767x; 1.0767x over previous
//
#include <hip/hip_runtime.h>

// B=2, F=T=2048, HIDDEN=1024 (16 heads x 64)
// Round 17 = round-16 with ONE change: attn __launch_bounds__(512,4)->(512,2).
// Diagnosis: attn has reported EXACTLY 64 VGPRs every round -- the (512,4)
// bound caps the allocator at 64 regs; r6 and r10 both overflowed the cap and
// spilled (VGPR pinned 64 + WRITE_SIZE explosion + low MfmaUtil). LDS (68 KB)
// already limits attn to 2 blocks/CU = 4 waves/SIMD, so relaxing the bound
// cannot reduce achieved occupancy -- it only stops scratch spill.
// attn structure (verified correct in r16, absmax 4.88e-4): V read L2-direct
// (Vt[head][h][t] is PV-A-fragment-native), K double-buffered, ONE barrier/iter,
// K staged via T14 reg-prefetch. prep/gemm = round-8 verbatim.

typedef short v8s __attribute__((ext_vector_type(8)));
typedef float v4f __attribute__((ext_vector_type(4)));
typedef unsigned short u16;
typedef unsigned int   u32;
typedef unsigned long long u64;

constexpr float QSCALE = 0.18033688011112042f;  // 0.125 * log2(e)

__device__ __forceinline__ u16 f2bf(float f) {
    u32 u = __builtin_bit_cast(u32, f);
    u += 0x7fffu + ((u >> 16) & 1u);
    return (u16)(u >> 16);
}

// truncating bf16 pair pack: {b[31:16], a[31:16]} in ONE v_perm_b32
__device__ __forceinline__ u32 pack_trunc(float a, float b) {
    return __builtin_amdgcn_perm(__builtin_bit_cast(u32, b),
                                 __builtin_bit_cast(u32, a), 0x07060302u);
}

// ROUNDING bf16 pair pack (same rounding as f2bf)
__device__ __forceinline__ u32 pack_rnd(u32 ua, u32 ub) {
    ua += 0x7fffu + ((ua >> 16) & 1u);
    ub += 0x7fffu + ((ub >> 16) & 1u);
    return __builtin_amdgcn_perm(ub, ua, 0x07060302u);
}

// 8 fp32 (2 uint4) -> 8 bf16 (1 uint4), element order preserved
__device__ __forceinline__ uint4 cvt8(uint4 lo, uint4 hi) {
    uint4 r;
    r.x = pack_rnd(lo.x, lo.y);
    r.y = pack_rnd(lo.z, lo.w);
    r.z = pack_rnd(hi.x, hi.y);
    r.w = pack_rnd(hi.z, hi.w);
    return r;
}

__device__ __forceinline__ v8s ld8(const u16* p) {
    return *reinterpret_cast<const v8s*>(p);
}

// ---------------- prep: W transpose+cvt | mask pack (batched) ----------------
__global__ __launch_bounds__(256) void prep(
    const float* __restrict__ Wq, const float* __restrict__ Wk, const float* __restrict__ Wv,
    u16* __restrict__ Wqt, u16* __restrict__ Wkt, u16* __restrict__ Wvt,
    const int* __restrict__ mask, u64* __restrict__ words) {
    __shared__ float tile[32][33];
    const int bid = blockIdx.x, tid = threadIdx.x;
    if (bid < 3072) {
        const int zz = bid >> 10, rem = bid & 1023;
        const float* W = zz == 0 ? Wq : (zz == 1 ? Wk : Wv);
        u16* Wt = zz == 0 ? Wqt : (zz == 1 ? Wkt : Wvt);
        const int tx = tid & 31, ty = tid >> 5;
        const int n0 = (rem & 31) * 32, k0 = (rem >> 5) * 32;
        for (int i = 0; i < 4; i++)
            tile[ty + i * 8][tx] = W[(size_t)(k0 + ty + i * 8) * 1024 + n0 + tx];
        __syncthreads();
        for (int i = 0; i < 4; i++)
            Wt[(size_t)(n0 + ty + i * 8) * 1024 + k0 + tx] = f2bf(tile[tx][ty + i * 8]);
    } else {
        // mask pack: 4096 blocks x 4 waves x 8 words (64 ints each), ILP 8
        const int lane = tid & 63;
        const int g0 = (bid - 3072) * 32 + (tid >> 6) * 8;
        const int* mp = mask + (size_t)g0 * 64 + lane;
        u64* wp = words + g0;
        #pragma unroll
        for (int i = 0; i < 8; i++) {
            const u64 bits = __ballot(mp[(size_t)i * 64] != 0);
            if (lane == 0) wp[i] = bits;
        }
    }
}

// ---------------- z-fused bf16 GEMM, BK=64: C[4096][1024] = A @ W^T + bias ----
__global__ __launch_bounds__(256, 3) void gemm_qkv(
    const float* __restrict__ Xf32, const float* __restrict__ Xt32,
    const u16* __restrict__ Wqt, const u16* __restrict__ Wkt, const u16* __restrict__ Wvt,
    const float* __restrict__ bq, const float* __restrict__ bk, const float* __restrict__ bv,
    u16* __restrict__ Qb, u16* __restrict__ Kb, u16* __restrict__ Vtb) {
    const int z = blockIdx.z;
    const float* A    = z == 0 ? Xf32 : Xt32;
    const u16* Bt     = z == 0 ? Wqt : (z == 1 ? Wkt : Wvt);
    const float* bias = z == 0 ? bq : (z == 1 ? bk : bv);
    u16* C            = z == 0 ? Qb : (z == 1 ? Kb : Vtb);
    const int mode    = (z == 2);
    const float sc    = (z == 0) ? QSCALE : 1.0f;

    __shared__ u16 As[2][128][32];   // [khalf][row][32] 16 KB
    __shared__ u16 Bs[2][128][32];
    const uint4* Ag = reinterpret_cast<const uint4*>(A);   // fp32: 256 uint4/row
    const uint4* Bg = reinterpret_cast<const uint4*>(Bt);  // bf16: 128 uint4/row

    const int tid = threadIdx.x;
    const int lane = tid & 63, wave = tid >> 6;
    const int quad = lane >> 4, l16 = lane & 15;
    const int wm = wave >> 1, wn = wave & 1;
    const int m0 = blockIdx.x * 128, n0 = blockIdx.y * 128;

    const int cg  = (lane & 3) ^ ((lane >> 3) & 3);
    const int sw8 = (quad ^ ((l16 >> 1) & 3)) * 8;

    const int gi0 = wave * 4;
    const uint4 *ap0, *ap1, *ap2, *ap3, *bp0, *bp1, *bp2, *bp3;
    {
        const int rl = lane >> 2;
        const int rb0 = ((gi0 + 0) & 7) * 16 + rl, kh0 = (gi0 + 0) >> 3;
        const int rb1 = ((gi0 + 1) & 7) * 16 + rl, kh1 = (gi0 + 1) >> 3;
        const int rb2 = ((gi0 + 2) & 7) * 16 + rl, kh2 = (gi0 + 2) >> 3;
        const int rb3 = ((gi0 + 3) & 7) * 16 + rl, kh3 = (gi0 + 3) >> 3;
        // fp32 A: lane covers 8 floats = 2 consecutive uint4 at (kh*4+cg)*2
        ap0 = Ag + (size_t)(m0 + rb0) * 256 + (kh0 * 4 + cg) * 2;
        ap1 = Ag + (size_t)(m0 + rb1) * 256 + (kh1 * 4 + cg) * 2;
        ap2 = Ag + (size_t)(m0 + rb2) * 256 + (kh2 * 4 + cg) * 2;
        ap3 = Ag + (size_t)(m0 + rb3) * 256 + (kh3 * 4 + cg) * 2;
        bp0 = Bg + (size_t)(n0 + rb0) * 128 + kh0 * 4 + cg;
        bp1 = Bg + (size_t)(n0 + rb1) * 128 + kh1 * 4 + cg;
        bp2 = Bg + (size_t)(n0 + rb2) * 128 + kh2 * 4 + cg;
        bp3 = Bg + (size_t)(n0 + rb3) * 128 + kh3 * 4 + cg;
    }
    uint4* da = reinterpret_cast<uint4*>((u16*)As + gi0 * 512) + lane;
    uint4* db = reinterpret_cast<uint4*>((u16*)Bs + gi0 * 512) + lane;

    v4f acc[4][4];
    for (int i = 0; i < 4; i++)
        for (int j = 0; j < 4; j++) acc[i][j] = (v4f)0.0f;

    // prologue: load K-slice 0 (A fp32 raw + B bf16), convert A
    uint4 a0l = ap0[0], a0h = ap0[1]; ap0 += 16;
    uint4 a1l = ap1[0], a1h = ap1[1]; ap1 += 16;
    uint4 a2l = ap2[0], a2h = ap2[1]; ap2 += 16;
    uint4 a3l = ap3[0], a3h = ap3[1]; ap3 += 16;
    uint4 sb0 = *bp0; bp0 += 8;
    uint4 sb1 = *bp1; bp1 += 8;
    uint4 sb2 = *bp2; bp2 += 8;
    uint4 sb3 = *bp3; bp3 += 8;
    uint4 ca0 = cvt8(a0l, a0h);
    uint4 ca1 = cvt8(a1l, a1h);
    uint4 ca2 = cvt8(a2l, a2h);
    uint4 ca3 = cvt8(a3l, a3h);

    for (int k0 = 0; k0 < 16; k0++) {
        __syncthreads();
        da[0]   = ca0;  da[64]  = ca1;  da[128] = ca2;  da[192] = ca3;
        db[0]   = sb0;  db[64]  = sb1;  db[128] = sb2;  db[192] = sb3;
        __syncthreads();

        if (k0 < 15) {
            a0l = ap0[0]; a0h = ap0[1]; ap0 += 16;
            a1l = ap1[0]; a1h = ap1[1]; ap1 += 16;
            a2l = ap2[0]; a2h = ap2[1]; ap2 += 16;
            a3l = ap3[0]; a3h = ap3[1]; ap3 += 16;
            sb0 = *bp0; bp0 += 8;
            sb1 = *bp1; bp1 += 8;
            sb2 = *bp2; bp2 += 8;
            sb3 = *bp3; bp3 += 8;
        }

        #pragma unroll
        for (int kk = 0; kk < 2; kk++) {
            v8s af[4], bf[4];
            #pragma unroll
            for (int mt = 0; mt < 4; mt++) af[mt] = ld8(&As[kk][wm * 64 + mt * 16 + l16][sw8]);
            #pragma unroll
            for (int nt = 0; nt < 4; nt++) bf[nt] = ld8(&Bs[kk][wn * 64 + nt * 16 + l16][sw8]);
            #pragma unroll
            for (int mt = 0; mt < 4; mt++)
                #pragma unroll
                for (int nt = 0; nt < 4; nt++)
                    acc[mt][nt] = __builtin_amdgcn_mfma_f32_16x16x32_bf16(af[mt], bf[nt], acc[mt][nt], 0, 0, 0);
        }

        if (k0 < 15) {               // convert AFTER compute: loads have arrived
            ca0 = cvt8(a0l, a0h);
            ca1 = cvt8(a1l, a1h);
            ca2 = cvt8(a2l, a2h);
            ca3 = cvt8(a3l, a3h);
        }
    }

    #pragma unroll
    for (int nt = 0; nt < 4; nt++) {
        const int col = n0 + wn * 64 + nt * 16 + l16;
        const float bvv = bias[col];
        #pragma unroll
        for (int mt = 0; mt < 4; mt++) {
            const int mbase = m0 + wm * 64 + mt * 16 + quad * 4;
            if (mode == 0) {
                for (int r = 0; r < 4; r++)
                    C[(size_t)(mbase + r) * 1024 + col] = f2bf((acc[mt][nt][r] + bvv) * sc);
            } else {
                const int b = mbase >> 11, t = mbase & 2047;
                const int head = col >> 6, h = col & 63;
                ushort4 pk;
                pk.x = f2bf(acc[mt][nt][0] + bvv);
                pk.y = f2bf(acc[mt][nt][1] + bvv);
                pk.z = f2bf(acc[mt][nt][2] + bvv);
                pk.w = f2bf(acc[mt][nt][3] + bvv);
                *reinterpret_cast<ushort4*>(&C[(size_t)((b * 16 + head) * 64 + h) * 2048 + t]) = pk;
            }
        }
    }
}

// ---------------- fused flash attention: V L2-direct, K double-buffered ----
// Q,K: bf16 [B][F/T][16][64] (Q pre-scaled); Vt: bf16 [B][16][64][2048]
// grid (32 bh, 16 f); block 512 = 8 waves. Wave w: q-rows (w&3)*32.., t-half w>>2.
// Per iter: ONE barrier. K(it+1) regs->ds_write into buf^1 (T14, 2 instr/wave);
// V fragments read straight from global (L2-hot, layout-native, no transpose);
// QK^T from Ks[buf]; softmax in-reg; P via per-wave LDS; PV with accL MFMA l-sum.
// launch_bounds (512,2): LDS already caps at 2 blocks/CU; this lifts the 64-VGPR
// allocator cap that caused r10's scratch spill.
__global__ __launch_bounds__(512, 2) void attn_fused(
    const u16* __restrict__ Qb, const u16* __restrict__ Kb,
    const u16* __restrict__ Vtb, const u64* __restrict__ mw,
    float* __restrict__ out) {
    __shared__ u16 Ks[2][2][2][64][32];  // [buf][thalf][khalf][t][32]  32 KB
    __shared__ u32 Ps[8 * 1152];         // per-wave P; epilogue buffer (36 KB)

    const int tid = threadIdx.x;
    const int lane = tid & 63, wave = tid >> 6;
    const int quad = lane >> 4, l16 = lane & 15;
    const int fwave = wave & 3, tw = wave >> 2;
    const int b = blockIdx.x >> 4, head = blockIdx.x & 15;
    const int f0 = blockIdx.y * 128;

    const uint4* Kg = reinterpret_cast<const uint4*>(Kb);
    const size_t vb16 = (size_t)(b * 16 + head) * 131072;   // u16 units

    const int cg  = (lane & 3) ^ ((lane >> 3) & 3);
    const int sw8 = (quad ^ ((l16 >> 1) & 3)) * 8;

    // Q-fragments in registers for the whole kernel (B-operand layout)
    v8s qf[2][2];
    #pragma unroll
    for (int kk = 0; kk < 2; kk++)
        #pragma unroll
        for (int qh = 0; qh < 2; qh++)
            qf[kk][qh] = ld8(Qb + ((size_t)(b * 2048 + f0 + fwave * 32 + qh * 16 + l16) * 16 + head) * 64
                                + kk * 32 + quad * 8);

    // ones A-fragment for the l-sum MFMA (bf16 1.0 = 0x3F80)
    v8s ones;
    #pragma unroll
    for (int i = 0; i < 8; i++) ones[i] = (short)0x3F80;

    // K staging: 16 instrs/iter over 8 waves = 2 per wave (T14 reg-prefetch).
    // Instr g covers 1 KB at (u16*)Ks + buf*8192 + g*512, lane slot lane*16 B.
    const uint4 *sp0, *sp1;
    {
        const int rl = lane >> 2;
        const int g0 = wave * 2;
        #define KPTR(g) (Kg + ((size_t)(b * 2048 + ((g) >> 3) * 1024 + ((g) & 3) * 16 + rl) * 16 + head) * 8 \
                            + (((g) >> 2) & 1) * 4 + cg)
        sp0 = KPTR(g0); sp1 = KPTR(g0 + 1);
        #undef KPTR
    }
    uint4* sd4a = reinterpret_cast<uint4*>((u16*)Ks + wave * 1024) + lane;          // buf0
    uint4* sd4b = reinterpret_cast<uint4*>((u16*)Ks + 8192 + wave * 1024) + lane;   // buf1

    v4f accO[2][4], accL[2];
    #pragma unroll
    for (int qh = 0; qh < 2; qh++) {
        accL[qh] = (v4f)0.0f;
        for (int ht = 0; ht < 4; ht++) accO[qh][ht] = (v4f)0.0f;
    }

    u32* myPs = Ps + wave * 1152;
    const u64* mrow = mw + (size_t)(b * 2048 + f0 + fwave * 32 + l16) * 32 + tw * 16;

    // prologue: K(0) -> regs -> buf0; K(1) -> regs; barrier
    uint4 k0a = *sp0; sp0 += 8192;
    uint4 k0b = *sp1; sp1 += 8192;
    sd4a[0]  = k0a;
    sd4a[64] = k0b;
    k0a = *sp0; sp0 += 8192;
    k0b = *sp1; sp1 += 8192;
    __syncthreads();

    for (int it = 0; it < 16; it++) {
        // stage K(it+1) into the write-buf; issue K(it+2) loads
        if (it < 15) {
            uint4* wd = (it & 1) ? sd4a : sd4b;
            wd[0]  = k0a;
            wd[64] = k0b;
            if (it < 14) {
                k0a = *sp0; sp0 += 8192;
                k0b = *sp1; sp1 += 8192;
            }
        }

        // V fragments for kk=0 issued EARLY (no barrier dependency; L2-hot);
        // they hide under QK^T + softmax.
        const u16* vpi = Vtb + vb16 + tw * 1024 + it * 64 + quad * 8;
        v8s vf0[4];
        #pragma unroll
        for (int ht = 0; ht < 4; ht++)
            vf0[ht] = ld8(vpi + (size_t)(ht * 16 + l16) * 2048);

        const u16* kb = (const u16*)Ks + (it & 1) * 8192;

        // S^T = K . Q^T : s[qh][mt], t = mt*16 + quad*4 + r, q-row = qh*16 + l16
        v4f s[2][4];
        #pragma unroll
        for (int qh = 0; qh < 2; qh++)
            for (int mt = 0; mt < 4; mt++) s[qh][mt] = (v4f)0.0f;
        #pragma unroll
        for (int kk = 0; kk < 2; kk++) {
            v8s kf[4];
            #pragma unroll
            for (int mt = 0; mt < 4; mt++)
                kf[mt] = ld8(kb + tw * 4096 + kk * 2048 + (mt * 16 + l16) * 32 + sw8);
            #pragma unroll
            for (int qh = 0; qh < 2; qh++)
                #pragma unroll
                for (int mt = 0; mt < 4; mt++)
                    s[qh][mt] = __builtin_amdgcn_mfma_f32_16x16x32_bf16(kf[mt], qf[kk][qh], s[qh][mt], 0, 0, 0);
        }

        // p = mask ? exp2(s) : 0  (no max pass; Q pre-scaled)
        u32 pk[2][8];
        #pragma unroll
        for (int qh = 0; qh < 2; qh++) {
            const u64 w = mrow[qh * 512 + it];
            const u32 lo = (u32)(w >> (quad * 4));
            const u32 hi = (u32)(w >> (quad * 4 + 32));
            #pragma unroll
            for (int mt = 0; mt < 4; mt++) {
                const u32 bits = ((mt & 2) ? hi : lo) >> ((mt & 1) * 16);
                float p[4];
                #pragma unroll
                for (int r = 0; r < 4; r++) {
                    const float e = __builtin_amdgcn_exp2f(s[qh][mt][r]);
                    p[r] = ((bits >> r) & 1u) ? e : 0.0f;
                }
                pk[qh][mt * 2]     = pack_trunc(p[0], p[1]);
                pk[qh][mt * 2 + 1] = pack_trunc(p[2], p[3]);
            }
        }

        // P -> per-wave LDS (wave-private: no barrier)
        #pragma unroll
        for (int qh = 0; qh < 2; qh++) {
            const int row = qh * 16 + l16;
            #pragma unroll
            for (int mt = 0; mt < 4; mt++)
                *reinterpret_cast<uint2*>(&myPs[row * 36 + mt * 8 + quad * 2]) =
                    make_uint2(pk[qh][mt * 2], pk[qh][mt * 2 + 1]);
        }

        // O^T += V . P^T ; l += ones . P^T  (same rounded P as numerator)
        #pragma unroll
        for (int kk = 0; kk < 2; kk++) {
            v8s vf[4];
            #pragma unroll
            for (int ht = 0; ht < 4; ht++)
                vf[ht] = (kk == 0) ? vf0[ht]
                                   : ld8(vpi + (size_t)(ht * 16 + l16) * 2048 + 32);
            #pragma unroll
            for (int qh = 0; qh < 2; qh++) {
                const v8s pf = *reinterpret_cast<const v8s*>(
                    &myPs[(qh * 16 + l16) * 36 + kk * 16 + quad * 4]);
                #pragma unroll
                for (int ht = 0; ht < 4; ht++)
                    accO[qh][ht] = __builtin_amdgcn_mfma_f32_16x16x32_bf16(vf[ht], pf, accO[qh][ht], 0, 0, 0);
                accL[qh] = __builtin_amdgcn_mfma_f32_16x16x32_bf16(ones, pf, accL[qh], 0, 0, 0);
            }
        }

        __syncthreads();             // single barrier: buf swap + Ps reuse safety
    }

    // ---- epilogue: combine the two t-halves in LDS ----
    float* fb = (float*)Ps;               // 9216 floats: 4 regions x 64 lanes x 36
    if (tw == 1) {
        float* wdst = fb + fwave * 2304 + lane * 36;
        #pragma unroll
        for (int qh = 0; qh < 2; qh++)
            #pragma unroll
            for (int ht = 0; ht < 4; ht++)
                *reinterpret_cast<v4f*>(wdst + (qh * 4 + ht) * 4) = accO[qh][ht];
        wdst[32] = accL[0][0];
        wdst[33] = accL[1][0];
    }
    __syncthreads();
    if (tw == 0) {
        const float* rsrc = fb + fwave * 2304 + lane * 36;
        float inv[2];
        #pragma unroll
        for (int qh = 0; qh < 2; qh++)
            inv[qh] = 1.0f / (accL[qh][0] + rsrc[32 + qh]);
        #pragma unroll
        for (int qh = 0; qh < 2; qh++) {
            const size_t ro = (size_t)(b * 2048 + f0 + fwave * 32 + qh * 16 + l16) * 1024 + head * 64;
            #pragma unroll
            for (int ht = 0; ht < 4; ht++) {
                const v4f p = *reinterpret_cast<const v4f*>(rsrc + (qh * 4 + ht) * 4);
                float4 o;
                o.x = (accO[qh][ht][0] + p[0]) * inv[qh];
                o.y = (accO[qh][ht][1] + p[1]) * inv[qh];
                o.z = (accO[qh][ht][2] + p[2]) * inv[qh];
                o.w = (accO[qh][ht][3] + p[3]) * inv[qh];
                *reinterpret_cast<float4*>(&out[ro + ht * 16 + quad * 4]) = o;
            }
        }
    }
}

extern "C" void kernel_launch(void* const* d_in, const int* in_sizes, int n_in,
                              void* d_out, int out_size, void* d_ws, size_t ws_size,
                              hipStream_t stream) {
    const float* from = (const float*)d_in[0];
    const float* to   = (const float*)d_in[1];
    const int*   mask = (const int*)d_in[2];
    const float* Wq = (const float*)d_in[3];
    const float* bq = (const float*)d_in[4];
    const float* Wk = (const float*)d_in[5];
    const float* bk = (const float*)d_in[6];
    const float* Wv = (const float*)d_in[7];
    const float* bv = (const float*)d_in[8];
    float* out = (float*)d_out;

    u16* Wqt = (u16*)d_ws;            // 1024x1024 bf16 each
    u16* Wkt = Wqt + 1048576;
    u16* Wvt = Wkt + 1048576;
    u16* Qb  = Wvt + 1048576;         // 4096x1024
    u16* Kb  = Qb  + 4194304;
    u16* Vtb = Kb  + 4194304;         // [2][16][64][2048]
    u64* mwords = (u64*)(Vtb + 4194304);  // 2*2048*32 words, row-major [row][tword]

    prep<<<7168, 256, 0, stream>>>(Wq, Wk, Wv, Wqt, Wkt, Wvt, mask, mwords);

    gemm_qkv<<<dim3(32, 8, 3), 256, 0, stream>>>(from, to, Wqt, Wkt, Wvt, bq, bk, bv,
                                                 Qb, Kb, Vtb);

    attn_fused<<<dim3(32, 16), 512, 0, stream>>>(Qb, Kb, Vtb, mwords, out);
}

// Round 12
// 212.082 us; speedup vs baseline: 1.2877x; 1.1960x over previous
//
#include <hip/hip_runtime.h>

// B=2, F=T=2048, HIDDEN=1024 (16 heads x 64)
// FINAL = round-8 configuration verbatim (best verified: 213.09 us).
//  - prep: W transpose+cvt | batched mask pack (7168 blocks)
//  - gemm_qkv: fp32-A direct read + fused bf16 cvt in T14 reg-prefetch staging
//  - attn_fused: round-1/7 structure -- 16x16 MFMA S^T form, in-block t-split,
//    T14 reg-prefetch K/V staging, v_perm pack, MFMA-pipe l-sum.
// Measured dead ends (all reverted): 32x32 attn rebuild (r8-10 orig), VALU
// l-sum, transposed mask words (XCD ping-pong), mask-in-gemm z-tail, setprio
// in MFMA bodies (spill under 64-VGPR cap), V-L2-direct + K-dbuf (latency-
// bound even after (512,2) lifted the cap and killed the spill: 97.7 us).
// Key compiler fact learned: __launch_bounds__(512,4) caps attn at 64 VGPR.

typedef short v8s __attribute__((ext_vector_type(8)));
typedef float v4f __attribute__((ext_vector_type(4)));
typedef unsigned short u16;
typedef unsigned int   u32;
typedef unsigned long long u64;

constexpr float QSCALE = 0.18033688011112042f;  // 0.125 * log2(e)

__device__ __forceinline__ u16 f2bf(float f) {
    u32 u = __builtin_bit_cast(u32, f);
    u += 0x7fffu + ((u >> 16) & 1u);
    return (u16)(u >> 16);
}

// truncating bf16 pair pack: {b[31:16], a[31:16]} in ONE v_perm_b32
__device__ __forceinline__ u32 pack_trunc(float a, float b) {
    return __builtin_amdgcn_perm(__builtin_bit_cast(u32, b),
                                 __builtin_bit_cast(u32, a), 0x07060302u);
}

// ROUNDING bf16 pair pack (same rounding as f2bf)
__device__ __forceinline__ u32 pack_rnd(u32 ua, u32 ub) {
    ua += 0x7fffu + ((ua >> 16) & 1u);
    ub += 0x7fffu + ((ub >> 16) & 1u);
    return __builtin_amdgcn_perm(ub, ua, 0x07060302u);
}

// 8 fp32 (2 uint4) -> 8 bf16 (1 uint4), element order preserved
__device__ __forceinline__ uint4 cvt8(uint4 lo, uint4 hi) {
    uint4 r;
    r.x = pack_rnd(lo.x, lo.y);
    r.y = pack_rnd(lo.z, lo.w);
    r.z = pack_rnd(hi.x, hi.y);
    r.w = pack_rnd(hi.z, hi.w);
    return r;
}

__device__ __forceinline__ v8s ld8(const u16* p) {
    return *reinterpret_cast<const v8s*>(p);
}

// ---------------- prep: W transpose+cvt | mask pack (batched) ----------------
__global__ __launch_bounds__(256) void prep(
    const float* __restrict__ Wq, const float* __restrict__ Wk, const float* __restrict__ Wv,
    u16* __restrict__ Wqt, u16* __restrict__ Wkt, u16* __restrict__ Wvt,
    const int* __restrict__ mask, u64* __restrict__ words) {
    __shared__ float tile[32][33];
    const int bid = blockIdx.x, tid = threadIdx.x;
    if (bid < 3072) {
        const int zz = bid >> 10, rem = bid & 1023;
        const float* W = zz == 0 ? Wq : (zz == 1 ? Wk : Wv);
        u16* Wt = zz == 0 ? Wqt : (zz == 1 ? Wkt : Wvt);
        const int tx = tid & 31, ty = tid >> 5;
        const int n0 = (rem & 31) * 32, k0 = (rem >> 5) * 32;
        for (int i = 0; i < 4; i++)
            tile[ty + i * 8][tx] = W[(size_t)(k0 + ty + i * 8) * 1024 + n0 + tx];
        __syncthreads();
        for (int i = 0; i < 4; i++)
            Wt[(size_t)(n0 + ty + i * 8) * 1024 + k0 + tx] = f2bf(tile[tx][ty + i * 8]);
    } else {
        // mask pack: 4096 blocks x 4 waves x 8 words (64 ints each), ILP 8
        const int lane = tid & 63;
        const int g0 = (bid - 3072) * 32 + (tid >> 6) * 8;
        const int* mp = mask + (size_t)g0 * 64 + lane;
        u64* wp = words + g0;
        #pragma unroll
        for (int i = 0; i < 8; i++) {
            const u64 bits = __ballot(mp[(size_t)i * 64] != 0);
            if (lane == 0) wp[i] = bits;
        }
    }
}

// ---------------- z-fused bf16 GEMM, BK=64: C[4096][1024] = A @ W^T + bias ----
// A side reads fp32 from/to directly; cvt to bf16 at the end of the compute
// phase (loads long arrived), ds_write in the minimal barrier window.
__global__ __launch_bounds__(256, 3) void gemm_qkv(
    const float* __restrict__ Xf32, const float* __restrict__ Xt32,
    const u16* __restrict__ Wqt, const u16* __restrict__ Wkt, const u16* __restrict__ Wvt,
    const float* __restrict__ bq, const float* __restrict__ bk, const float* __restrict__ bv,
    u16* __restrict__ Qb, u16* __restrict__ Kb, u16* __restrict__ Vtb) {
    const int z = blockIdx.z;
    const float* A    = z == 0 ? Xf32 : Xt32;
    const u16* Bt     = z == 0 ? Wqt : (z == 1 ? Wkt : Wvt);
    const float* bias = z == 0 ? bq : (z == 1 ? bk : bv);
    u16* C            = z == 0 ? Qb : (z == 1 ? Kb : Vtb);
    const int mode    = (z == 2);
    const float sc    = (z == 0) ? QSCALE : 1.0f;

    __shared__ u16 As[2][128][32];   // [khalf][row][32] 16 KB
    __shared__ u16 Bs[2][128][32];
    const uint4* Ag = reinterpret_cast<const uint4*>(A);   // fp32: 256 uint4/row
    const uint4* Bg = reinterpret_cast<const uint4*>(Bt);  // bf16: 128 uint4/row

    const int tid = threadIdx.x;
    const int lane = tid & 63, wave = tid >> 6;
    const int quad = lane >> 4, l16 = lane & 15;
    const int wm = wave >> 1, wn = wave & 1;
    const int m0 = blockIdx.x * 128, n0 = blockIdx.y * 128;

    const int cg  = (lane & 3) ^ ((lane >> 3) & 3);
    const int sw8 = (quad ^ ((l16 >> 1) & 3)) * 8;

    const int gi0 = wave * 4;
    const uint4 *ap0, *ap1, *ap2, *ap3, *bp0, *bp1, *bp2, *bp3;
    {
        const int rl = lane >> 2;
        const int rb0 = ((gi0 + 0) & 7) * 16 + rl, kh0 = (gi0 + 0) >> 3;
        const int rb1 = ((gi0 + 1) & 7) * 16 + rl, kh1 = (gi0 + 1) >> 3;
        const int rb2 = ((gi0 + 2) & 7) * 16 + rl, kh2 = (gi0 + 2) >> 3;
        const int rb3 = ((gi0 + 3) & 7) * 16 + rl, kh3 = (gi0 + 3) >> 3;
        // fp32 A: lane covers 8 floats = 2 consecutive uint4 at (kh*4+cg)*2
        ap0 = Ag + (size_t)(m0 + rb0) * 256 + (kh0 * 4 + cg) * 2;
        ap1 = Ag + (size_t)(m0 + rb1) * 256 + (kh1 * 4 + cg) * 2;
        ap2 = Ag + (size_t)(m0 + rb2) * 256 + (kh2 * 4 + cg) * 2;
        ap3 = Ag + (size_t)(m0 + rb3) * 256 + (kh3 * 4 + cg) * 2;
        bp0 = Bg + (size_t)(n0 + rb0) * 128 + kh0 * 4 + cg;
        bp1 = Bg + (size_t)(n0 + rb1) * 128 + kh1 * 4 + cg;
        bp2 = Bg + (size_t)(n0 + rb2) * 128 + kh2 * 4 + cg;
        bp3 = Bg + (size_t)(n0 + rb3) * 128 + kh3 * 4 + cg;
    }
    uint4* da = reinterpret_cast<uint4*>((u16*)As + gi0 * 512) + lane;
    uint4* db = reinterpret_cast<uint4*>((u16*)Bs + gi0 * 512) + lane;

    v4f acc[4][4];
    for (int i = 0; i < 4; i++)
        for (int j = 0; j < 4; j++) acc[i][j] = (v4f)0.0f;

    // prologue: load K-slice 0 (A fp32 raw + B bf16), convert A
    uint4 a0l = ap0[0], a0h = ap0[1]; ap0 += 16;
    uint4 a1l = ap1[0], a1h = ap1[1]; ap1 += 16;
    uint4 a2l = ap2[0], a2h = ap2[1]; ap2 += 16;
    uint4 a3l = ap3[0], a3h = ap3[1]; ap3 += 16;
    uint4 sb0 = *bp0; bp0 += 8;
    uint4 sb1 = *bp1; bp1 += 8;
    uint4 sb2 = *bp2; bp2 += 8;
    uint4 sb3 = *bp3; bp3 += 8;
    uint4 ca0 = cvt8(a0l, a0h);
    uint4 ca1 = cvt8(a1l, a1h);
    uint4 ca2 = cvt8(a2l, a2h);
    uint4 ca3 = cvt8(a3l, a3h);

    for (int k0 = 0; k0 < 16; k0++) {
        __syncthreads();
        da[0]   = ca0;  da[64]  = ca1;  da[128] = ca2;  da[192] = ca3;
        db[0]   = sb0;  db[64]  = sb1;  db[128] = sb2;  db[192] = sb3;
        __syncthreads();

        if (k0 < 15) {
            a0l = ap0[0]; a0h = ap0[1]; ap0 += 16;
            a1l = ap1[0]; a1h = ap1[1]; ap1 += 16;
            a2l = ap2[0]; a2h = ap2[1]; ap2 += 16;
            a3l = ap3[0]; a3h = ap3[1]; ap3 += 16;
            sb0 = *bp0; bp0 += 8;
            sb1 = *bp1; bp1 += 8;
            sb2 = *bp2; bp2 += 8;
            sb3 = *bp3; bp3 += 8;
        }

        #pragma unroll
        for (int kk = 0; kk < 2; kk++) {
            v8s af[4], bf[4];
            #pragma unroll
            for (int mt = 0; mt < 4; mt++) af[mt] = ld8(&As[kk][wm * 64 + mt * 16 + l16][sw8]);
            #pragma unroll
            for (int nt = 0; nt < 4; nt++) bf[nt] = ld8(&Bs[kk][wn * 64 + nt * 16 + l16][sw8]);
            #pragma unroll
            for (int mt = 0; mt < 4; mt++)
                #pragma unroll
                for (int nt = 0; nt < 4; nt++)
                    acc[mt][nt] = __builtin_amdgcn_mfma_f32_16x16x32_bf16(af[mt], bf[nt], acc[mt][nt], 0, 0, 0);
        }

        if (k0 < 15) {               // convert AFTER compute: loads have arrived
            ca0 = cvt8(a0l, a0h);
            ca1 = cvt8(a1l, a1h);
            ca2 = cvt8(a2l, a2h);
            ca3 = cvt8(a3l, a3h);
        }
    }

    #pragma unroll
    for (int nt = 0; nt < 4; nt++) {
        const int col = n0 + wn * 64 + nt * 16 + l16;
        const float bvv = bias[col];
        #pragma unroll
        for (int mt = 0; mt < 4; mt++) {
            const int mbase = m0 + wm * 64 + mt * 16 + quad * 4;
            if (mode == 0) {
                for (int r = 0; r < 4; r++)
                    C[(size_t)(mbase + r) * 1024 + col] = f2bf((acc[mt][nt][r] + bvv) * sc);
            } else {
                const int b = mbase >> 11, t = mbase & 2047;
                const int head = col >> 6, h = col & 63;
                ushort4 pk;
                pk.x = f2bf(acc[mt][nt][0] + bvv);
                pk.y = f2bf(acc[mt][nt][1] + bvv);
                pk.z = f2bf(acc[mt][nt][2] + bvv);
                pk.w = f2bf(acc[mt][nt][3] + bvv);
                *reinterpret_cast<ushort4*>(&C[(size_t)((b * 16 + head) * 64 + h) * 2048 + t]) = pk;
            }
        }
    }
}

// ---------------- fused flash attention, in-block t-split (round-7 verbatim) ----
// Q,K: bf16 [B][F/T][16][64] (Q pre-scaled); Vt: bf16 [B][16][64][2048]
// grid (32 bh, 16 f); block 512 = 8 waves. Wave w: q-rows (w&3)*32.., t-half w>>2.
// T14 staging: K/V loads for it+1 issued at top of compute(it) into registers;
// after the tile barrier the regs are ds_write_b128'd (LDS image = global_load_lds).
__global__ __launch_bounds__(512, 4) void attn_fused(
    const u16* __restrict__ Qb, const u16* __restrict__ Kb,
    const u16* __restrict__ Vtb, const u64* __restrict__ mw,
    float* __restrict__ out) {
    __shared__ u16 Ks[2][2][64][32];   // [thalf][khalf][t][32]  16 KB
    __shared__ u16 Vs[2][2][64][32];   // [thalf][tsub][h][32]   16 KB
    __shared__ u32 Ps[8 * 1152];       // per-wave P; reused as epilogue buffer (36 KB)

    const int tid = threadIdx.x;
    const int lane = tid & 63, wave = tid >> 6;
    const int quad = lane >> 4, l16 = lane & 15;
    const int fwave = wave & 3, tw = wave >> 2;
    const int b = blockIdx.x >> 4, head = blockIdx.x & 15;
    const int f0 = blockIdx.y * 128;

    const uint4* Kg = reinterpret_cast<const uint4*>(Kb);
    const uint4* Vg = reinterpret_cast<const uint4*>(Vtb);
    const size_t vbase4 = (size_t)(b * 16 + head) * 64 * 256;

    const int cg  = (lane & 3) ^ ((lane >> 3) & 3);
    const int sw8 = (quad ^ ((l16 >> 1) & 3)) * 8;

    // Q-fragments in registers for the whole kernel (B-operand layout)
    v8s qf[2][2];
    #pragma unroll
    for (int kk = 0; kk < 2; kk++)
        #pragma unroll
        for (int qh = 0; qh < 2; qh++)
            qf[kk][qh] = ld8(Qb + ((size_t)(b * 2048 + f0 + fwave * 32 + qh * 16 + l16) * 16 + head) * 64
                                + kk * 32 + quad * 8);

    // ones A-fragment for the l-sum MFMA (bf16 1.0 = 0x3F80)
    v8s ones;
    #pragma unroll
    for (int i = 0; i < 8; i++) ones[i] = (short)0x3F80;

    // staging: 32 loads/iter (16 K + 16 V), 4 per wave; waves 0-3 K, 4-7 V
    const uint4 *sp0, *sp1, *sp2, *sp3;
    u16 *sd;
    size_t sinc;
    {
        const int rl = lane >> 2;
        if (wave < 4) {
            const int g0 = wave * 4;
            sd = (u16*)Ks + g0 * 512;
            sinc = 8192;
            #define KPTR(g) (Kg + ((size_t)(b * 2048 + ((g) >> 3) * 1024 + ((g) & 3) * 16 + rl) * 16 + head) * 8 \
                                + (((g) >> 2) & 1) * 4 + cg)
            sp0 = KPTR(g0); sp1 = KPTR(g0 + 1); sp2 = KPTR(g0 + 2); sp3 = KPTR(g0 + 3);
            #undef KPTR
        } else {
            const int g0 = (wave - 4) * 4;
            sd = (u16*)Vs + g0 * 512;
            sinc = 8;
            #define VPTR(g) (Vg + vbase4 + (size_t)(((g) & 3) * 16 + rl) * 256 + ((g) >> 3) * 128 \
                                + (((g) >> 2) & 1) * 4 + cg)
            sp0 = VPTR(g0); sp1 = VPTR(g0 + 1); sp2 = VPTR(g0 + 2); sp3 = VPTR(g0 + 3);
            #undef VPTR
        }
    }
    // per-lane LDS dest: wave-uniform base + lane*16B (matches global_load_lds layout)
    uint4* sd4 = reinterpret_cast<uint4*>(sd) + lane;

    v4f accO[2][4], accL[2];
    #pragma unroll
    for (int qh = 0; qh < 2; qh++) {
        accL[qh] = (v4f)0.0f;
        for (int ht = 0; ht < 4; ht++) accO[qh][ht] = (v4f)0.0f;
    }

    u32* myPs = Ps + wave * 1152;
    const u64* mrow = mw + (size_t)(b * 2048 + f0 + fwave * 32 + l16) * 32 + tw * 16;

    // prologue: prefetch tile 0 into registers
    uint4 st0 = *sp0; sp0 += sinc;
    uint4 st1 = *sp1; sp1 += sinc;
    uint4 st2 = *sp2; sp2 += sinc;
    uint4 st3 = *sp3; sp3 += sinc;

    for (int it = 0; it < 16; it++) {
        __syncthreads();             // all waves done reading Ks/Vs for it-1
        sd4[0]   = st0;
        sd4[64]  = st1;
        sd4[128] = st2;
        sd4[192] = st3;
        __syncthreads();             // tile visible to all waves

        // issue prefetch for it+1 NOW; it completes under ~700cy of compute
        if (it < 15) {
            st0 = *sp0; sp0 += sinc;
            st1 = *sp1; sp1 += sinc;
            st2 = *sp2; sp2 += sinc;
            st3 = *sp3; sp3 += sinc;
        }

        // S^T = K . Q^T : s[qh][mt], t = mt*16 + quad*4 + r, q-row = qh*16 + l16
        v4f s[2][4];
        #pragma unroll
        for (int qh = 0; qh < 2; qh++)
            for (int mt = 0; mt < 4; mt++) s[qh][mt] = (v4f)0.0f;
        #pragma unroll
        for (int kk = 0; kk < 2; kk++) {
            v8s kf[4];
            #pragma unroll
            for (int mt = 0; mt < 4; mt++) kf[mt] = ld8(&Ks[tw][kk][mt * 16 + l16][sw8]);
            #pragma unroll
            for (int qh = 0; qh < 2; qh++)
                #pragma unroll
                for (int mt = 0; mt < 4; mt++)
                    s[qh][mt] = __builtin_amdgcn_mfma_f32_16x16x32_bf16(kf[mt], qf[kk][qh], s[qh][mt], 0, 0, 0);
        }

        // p = mask ? exp2(s) : 0  (no max pass; Q pre-scaled)
        u32 pk[2][8];
        #pragma unroll
        for (int qh = 0; qh < 2; qh++) {
            const u64 w = mrow[qh * 512 + it];
            const u32 lo = (u32)(w >> (quad * 4));
            const u32 hi = (u32)(w >> (quad * 4 + 32));
            #pragma unroll
            for (int mt = 0; mt < 4; mt++) {
                const u32 bits = ((mt & 2) ? hi : lo) >> ((mt & 1) * 16);
                float p[4];
                #pragma unroll
                for (int r = 0; r < 4; r++) {
                    const float e = __builtin_amdgcn_exp2f(s[qh][mt][r]);
                    p[r] = ((bits >> r) & 1u) ? e : 0.0f;
                }
                pk[qh][mt * 2]     = pack_trunc(p[0], p[1]);
                pk[qh][mt * 2 + 1] = pack_trunc(p[2], p[3]);
            }
        }

        // P -> per-wave LDS (wave-private: no barrier)
        #pragma unroll
        for (int qh = 0; qh < 2; qh++) {
            const int row = qh * 16 + l16;
            #pragma unroll
            for (int mt = 0; mt < 4; mt++)
                *reinterpret_cast<uint2*>(&myPs[row * 36 + mt * 8 + quad * 2]) =
                    make_uint2(pk[qh][mt * 2], pk[qh][mt * 2 + 1]);
        }

        // O^T += V . P^T ; l += ones . P^T  (same rounded P as numerator)
        #pragma unroll
        for (int kk = 0; kk < 2; kk++) {
            v8s vf[4];
            #pragma unroll
            for (int ht = 0; ht < 4; ht++) vf[ht] = ld8(&Vs[tw][kk][ht * 16 + l16][sw8]);
            #pragma unroll
            for (int qh = 0; qh < 2; qh++) {
                const v8s pf = *reinterpret_cast<const v8s*>(
                    &myPs[(qh * 16 + l16) * 36 + kk * 16 + quad * 4]);
                #pragma unroll
                for (int ht = 0; ht < 4; ht++)
                    accO[qh][ht] = __builtin_amdgcn_mfma_f32_16x16x32_bf16(vf[ht], pf, accO[qh][ht], 0, 0, 0);
                accL[qh] = __builtin_amdgcn_mfma_f32_16x16x32_bf16(ones, pf, accL[qh], 0, 0, 0);
            }
        }
    }

    // ---- epilogue: combine the two t-halves in LDS ----
    __syncthreads();                      // everyone done with Ps
    float* fb = (float*)Ps;               // 9216 floats: 4 regions x 64 lanes x 36
    if (tw == 1) {
        float* wdst = fb + fwave * 2304 + lane * 36;
        #pragma unroll
        for (int qh = 0; qh < 2; qh++)
            #pragma unroll
            for (int ht = 0; ht < 4; ht++)
                *reinterpret_cast<v4f*>(wdst + (qh * 4 + ht) * 4) = accO[qh][ht];
        wdst[32] = accL[0][0];
        wdst[33] = accL[1][0];
    }
    __syncthreads();
    if (tw == 0) {
        const float* rsrc = fb + fwave * 2304 + lane * 36;
        float inv[2];
        #pragma unroll
        for (int qh = 0; qh < 2; qh++)
            inv[qh] = 1.0f / (accL[qh][0] + rsrc[32 + qh]);
        #pragma unroll
        for (int qh = 0; qh < 2; qh++) {
            const size_t ro = (size_t)(b * 2048 + f0 + fwave * 32 + qh * 16 + l16) * 1024 + head * 64;
            #pragma unroll
            for (int ht = 0; ht < 4; ht++) {
                const v4f p = *reinterpret_cast<const v4f*>(rsrc + (qh * 4 + ht) * 4);
                float4 o;
                o.x = (accO[qh][ht][0] + p[0]) * inv[qh];
                o.y = (accO[qh][ht][1] + p[1]) * inv[qh];
                o.z = (accO[qh][ht][2] + p[2]) * inv[qh];
                o.w = (accO[qh][ht][3] + p[3]) * inv[qh];
                *reinterpret_cast<float4*>(&out[ro + ht * 16 + quad * 4]) = o;
            }
        }
    }
}

extern "C" void kernel_launch(void* const* d_in, const int* in_sizes, int n_in,
                              void* d_out, int out_size, void* d_ws, size_t ws_size,
                              hipStream_t stream) {
    const float* from = (const float*)d_in[0];
    const float* to   = (const float*)d_in[1];
    const int*   mask = (const int*)d_in[2];
    const float* Wq = (const float*)d_in[3];
    const float* bq = (const float*)d_in[4];
    const float* Wk = (const float*)d_in[5];
    const float* bk = (const float*)d_in[6];
    const float* Wv = (const float*)d_in[7];
    const float* bv = (const float*)d_in[8];
    float* out = (float*)d_out;

    u16* Wqt = (u16*)d_ws;            // 1024x1024 bf16 each
    u16* Wkt = Wqt + 1048576;
    u16* Wvt = Wkt + 1048576;
    u16* Qb  = Wvt + 1048576;         // 4096x1024
    u16* Kb  = Qb  + 4194304;
    u16* Vtb = Kb  + 4194304;         // [2][16][64][2048]
    u64* mwords = (u64*)(Vtb + 4194304);  // 2*2048*32 words, row-major [row][tword]

    prep<<<7168, 256, 0, stream>>>(Wq, Wk, Wv, Wqt, Wkt, Wvt, mask, mwords);

    gemm_qkv<<<dim3(32, 8, 3), 256, 0, stream>>>(from, to, Wqt, Wkt, Wvt, bq, bk, bv,
                                                 Qb, Kb, Vtb);

    attn_fused<<<dim3(32, 16), 512, 0, stream>>>(Qb, Kb, Vtb, mwords, out);
}